// Round 5
// baseline (269.541 us; speedup 1.0000x reference)
//
#include <hip/hip_runtime.h>

// BilateralSlice: grid [N=4, gh=16, gw=16, gd=8, C=12] f32, guide [4,1024,1024] f32
// out [N,H,W,C] f32.
// Each block = 256 consecutive pixels of one image row -> exactly 2 grid rows
// (cy0, cy1) needed = 12 KB. Stage them in LDS once, gather trilinear corners
// from LDS (kills divergent-L1 transaction replay), store dense from registers.

#define GH 16
#define GW 16
#define GD 8
#define NC 12
#define IMH 1024
#define IMW 1024
#define NBATCH 4
#define ROW_FLOATS (GW * GD * NC)   // 1536 floats = 6 KB per grid row
#define CELL_DW   (GD * NC)         // 96 dwords per (y,x) cell
#define Z_DW      (NC)              // 12 dwords per z slot

typedef float f32x4 __attribute__((ext_vector_type(4)));

__device__ __forceinline__ void fma4(f32x4& a, float w, const f32x4& v) {
    a = a + w * v;   // clang vector ops -> v_fmac_f32 x4
}

__global__ __launch_bounds__(256) void bilateral_slice_kernel(
    const float* __restrict__ grid,
    const float* __restrict__ guide,
    float* __restrict__ out)
{
    __shared__ float rowlds[2 * ROW_FLOATS];   // 12 KB: [row_sel][cx][cz][c]

    const int t = threadIdx.x;
    const int idx = blockIdx.x * 256 + t;      // flat pixel index, exact grid
    const int x = idx & (IMW - 1);
    const int y = (idx >> 10) & (IMH - 1);
    const int n = idx >> 20;

    // ---- y interpolation (uniform across the block: y is constant) ----
    const float gy = (y + 0.5f) * ((float)GH / (float)IMH);
    const float fy = floorf(gy - 0.5f);
    const int fyi = (int)fy;
    const int cy0 = min(max(fyi, 0), GH - 1);
    const int cy1 = min(max(fyi + 1, 0), GH - 1);
    float wy[2];
    wy[0] = fmaxf(1.0f - fabsf(fy + 0.5f - gy), 0.0f);
    wy[1] = fmaxf(1.0f - fabsf(fy + 1.5f - gy), 0.0f);

    // ---- stage the two needed grid rows into LDS (dense float4 loads) ----
    const float* gbase = grid + (size_t)n * (GH * ROW_FLOATS);
    const f32x4* src0 = (const f32x4*)(gbase + cy0 * ROW_FLOATS);
    const f32x4* src1 = (const f32x4*)(gbase + cy1 * ROW_FLOATS);
    f32x4* dst = (f32x4*)rowlds;
#pragma unroll
    for (int s = 0; s < 3; ++s) {              // 768 float4 total, 256 threads
        const int f = s * 256 + t;             // 0..767
        const int rs = (f >= 384) ? 1 : 0;     // which row
        const f32x4* src = rs ? src1 : src0;
        dst[f] = src[f - rs * 384];
    }

    // ---- per-pixel x/z interpolation setup ----
    const float gx = (x + 0.5f) * ((float)GW / (float)IMW);
    const float gz = guide[idx] * (float)GD;

    const float fx = floorf(gx - 0.5f);
    const float fz = floorf(gz - 0.5f);

    float wx[2], wz[2];
    int cx[2], cz[2];
#pragma unroll
    for (int i = 0; i < 2; ++i) {
        const float xx = fx + (float)i;
        const float zz = fz + (float)i;
        wx[i] = fmaxf(1.0f - fabsf(xx + 0.5f - gx), 0.0f);
        wz[i] = fmaxf(1.0f - fabsf(zz + 0.5f - gz), 0.0f);
        cx[i] = min(max((int)fx + i, 0), GW - 1);
        cz[i] = min(max((int)fz + i, 0), GD - 1);
    }

    __syncthreads();

    f32x4 a0 = (f32x4)0.f;
    f32x4 a1 = (f32x4)0.f;
    f32x4 a2 = (f32x4)0.f;

#pragma unroll
    for (int j = 0; j < 2; ++j) {
#pragma unroll
        for (int i = 0; i < 2; ++i) {
            const float wxy = wy[j] * wx[i];
            const int cellbase = j * ROW_FLOATS + cx[i] * CELL_DW;
#pragma unroll
            for (int k = 0; k < 2; ++k) {
                const float w = wxy * wz[k];
                const f32x4* g4 = (const f32x4*)&rowlds[cellbase + cz[k] * Z_DW];
                const f32x4 v0 = g4[0];
                const f32x4 v1 = g4[1];
                const f32x4 v2 = g4[2];
                fma4(a0, w, v0);
                fma4(a1, w, v1);
                fma4(a2, w, v2);
            }
        }
    }

    // ---- streamed output (never re-read): nontemporal stores ----
    f32x4* o = (f32x4*)(out + (size_t)idx * NC);
    __builtin_nontemporal_store(a0, o + 0);
    __builtin_nontemporal_store(a1, o + 1);
    __builtin_nontemporal_store(a2, o + 2);
}

extern "C" void kernel_launch(void* const* d_in, const int* in_sizes, int n_in,
                              void* d_out, int out_size, void* d_ws, size_t ws_size,
                              hipStream_t stream) {
    const float* grid  = (const float*)d_in[0];
    const float* guide = (const float*)d_in[1];
    float* out = (float*)d_out;

    const int total_pixels = NBATCH * IMH * IMW;     // 4,194,304
    const int block = 256;
    const int nblocks = total_pixels / block;        // 16384, exact

    bilateral_slice_kernel<<<nblocks, block, 0, stream>>>(grid, guide, out);
}

// Round 8
// 222.033 us; speedup vs baseline: 1.2140x; 1.2140x over previous
//
#include <hip/hip_runtime.h>

// BilateralSlice: grid [N=4, gh=16, gw=16, gd=8, C=12] f32, guide [4,1024,1024] f32
// out [N,H,W,C] f32.
// A/B vs R3: identical store path (LDS-staged dense stores); gathers moved
// from L1 (divergent 16B transactions) to LDS-staged grid rows (conflict-light).

#define GH 16
#define GW 16
#define GD 8
#define NC 12
#define IMH 1024
#define IMW 1024
#define NBATCH 4
#define ROW_FLOATS (GW * GD * NC)   // 1536 floats = 6 KB per grid row
#define CELL_DW   (GD * NC)         // 96 dwords per (y,x) cell
#define Z_DW      (NC)              // 12 dwords per z slot

typedef float f32x4 __attribute__((ext_vector_type(4)));

__device__ __forceinline__ void fma4(f32x4& a, float w, const f32x4& v) {
    a = a + w * v;
}

__global__ __launch_bounds__(256) void bilateral_slice_kernel(
    const float* __restrict__ grid,
    const float* __restrict__ guide,
    float* __restrict__ out)
{
    __shared__ float rowlds[2 * ROW_FLOATS];   // 12 KB: [row_sel][cx][cz][c]
    __shared__ f32x4 olds[3 * 256];            // 12 KB: out staging [part][pixel]

    const int t = threadIdx.x;
    const int idx = blockIdx.x * 256 + t;      // flat pixel index, exact grid
    const int x = idx & (IMW - 1);
    const int y = (idx >> 10) & (IMH - 1);
    const int n = idx >> 20;

    const float gz = guide[idx] * (float)GD;   // issue guide load early

    // ---- y interpolation (uniform across the block) ----
    const float gy = (y + 0.5f) * ((float)GH / (float)IMH);
    const float fy = floorf(gy - 0.5f);
    const int fyi = (int)fy;
    const int cy0 = min(max(fyi, 0), GH - 1);
    const int cy1 = min(max(fyi + 1, 0), GH - 1);
    float wy[2];
    wy[0] = fmaxf(1.0f - fabsf(fy + 0.5f - gy), 0.0f);
    wy[1] = fmaxf(1.0f - fabsf(fy + 1.5f - gy), 0.0f);

    // ---- stage the two needed grid rows into LDS (dense float4 loads) ----
    const float* gbase = grid + (size_t)n * (GH * ROW_FLOATS);
    const f32x4* src0 = (const f32x4*)(gbase + cy0 * ROW_FLOATS);
    const f32x4* src1 = (const f32x4*)(gbase + cy1 * ROW_FLOATS);
    f32x4* dst = (f32x4*)rowlds;
#pragma unroll
    for (int s = 0; s < 3; ++s) {              // 768 float4 total, 256 threads
        const int f = s * 256 + t;             // 0..767
        const int rs = (f >= 384) ? 1 : 0;
        const f32x4* src = rs ? src1 : src0;
        dst[f] = src[f - rs * 384];
    }

    // ---- per-pixel x/z setup (overlaps staging latency) ----
    const float gx = (x + 0.5f) * ((float)GW / (float)IMW);
    const float fx = floorf(gx - 0.5f);
    const float fz = floorf(gz - 0.5f);

    float wx[2], wz[2];
    int cx[2], cz[2];
#pragma unroll
    for (int i = 0; i < 2; ++i) {
        wx[i] = fmaxf(1.0f - fabsf(fx + (float)i + 0.5f - gx), 0.0f);
        wz[i] = fmaxf(1.0f - fabsf(fz + (float)i + 0.5f - gz), 0.0f);
        cx[i] = min(max((int)fx + i, 0), GW - 1);
        cz[i] = min(max((int)fz + i, 0), GD - 1);
    }

    __syncthreads();   // rows staged

    f32x4 a0 = (f32x4)0.f;
    f32x4 a1 = (f32x4)0.f;
    f32x4 a2 = (f32x4)0.f;

#pragma unroll
    for (int j = 0; j < 2; ++j) {
#pragma unroll
        for (int i = 0; i < 2; ++i) {
            const float wxy = wy[j] * wx[i];
            const int cellbase = j * ROW_FLOATS + cx[i] * CELL_DW;
#pragma unroll
            for (int k = 0; k < 2; ++k) {
                const float w = wxy * wz[k];
                const f32x4* g4 = (const f32x4*)&rowlds[cellbase + cz[k] * Z_DW];
                const f32x4 v0 = g4[0];
                const f32x4 v1 = g4[1];
                const f32x4 v2 = g4[2];
                fma4(a0, w, v0);
                fma4(a1, w, v1);
                fma4(a2, w, v2);
            }
        }
    }

    // ---- out staging (separate buffer -> no barrier needed before writes) ----
    olds[0 * 256 + t] = a0;
    olds[1 * 256 + t] = a1;
    olds[2 * 256 + t] = a2;
    __syncthreads();

    // Dense block-contiguous output: this block owns 768 float4s.
    f32x4* __restrict__ out4 = (f32x4*)out + (size_t)blockIdx.x * 768;
#pragma unroll
    for (int s = 0; s < 3; ++s) {
        const int e = s * 256 + t;            // flat float4 index within block
        const int p = e / 3;                  // local pixel
        const int part = e - 3 * p;
        out4[e] = olds[part * 256 + p];
    }
}

extern "C" void kernel_launch(void* const* d_in, const int* in_sizes, int n_in,
                              void* d_out, int out_size, void* d_ws, size_t ws_size,
                              hipStream_t stream) {
    const float* grid  = (const float*)d_in[0];
    const float* guide = (const float*)d_in[1];
    float* out = (float*)d_out;

    const int total_pixels = NBATCH * IMH * IMW;     // 4,194,304
    const int block = 256;
    const int nblocks = total_pixels / block;        // 16384, exact

    bilateral_slice_kernel<<<nblocks, block, 0, stream>>>(grid, guide, out);
}

// Round 16
// 221.674 us; speedup vs baseline: 1.2159x; 1.0016x over previous
//
#include <hip/hip_runtime.h>

// BilateralSlice: grid [N=4, gh=16, gw=16, gd=8, C=12] f32, guide [4,1024,1024] f32
// out [N,H,W,C] f32.
// R9: y-collapse factorization. Each block = 256 pixels of one image row.
// wy is block-uniform -> collapse the 2 needed grid rows into one
// y-interpolated row Y[16][8][12] (6 KB LDS) computed directly from global.
// Each thread then owns 3 flat output float4s (dense stores, no out staging);
// per float4: 4 LDS gathers (corners in x,z) instead of 8.

#define GH 16
#define GW 16
#define GD 8
#define NC 12
#define IMH 1024
#define IMW 1024
#define NBATCH 4
#define ROW_FLOATS (GW * GD * NC)   // 1536 floats = 6 KB per grid row
#define CELL_DW   (GD * NC)         // 96 dwords per x cell
#define Z_DW      (NC)              // 12 dwords per z slot

typedef float f32x4 __attribute__((ext_vector_type(4)));

__global__ __launch_bounds__(256) void bilateral_slice_kernel(
    const float* __restrict__ grid,
    const float* __restrict__ guide,
    float* __restrict__ out)
{
    __shared__ float yrow[ROW_FLOATS];         // 6 KB: [cx][cz][c], y-collapsed

    const int t = threadIdx.x;
    const int b = blockIdx.x;
    const int P0 = b * 256;                    // first pixel of this block
    const int y = (b >> 2) & (IMH - 1);        // 4 blocks per image row
    const int n = b >> 12;
    const int base_x = (b & 3) * 256;

    // ---- y interpolation (block-uniform) ----
    const float gy = (y + 0.5f) * ((float)GH / (float)IMH);
    const float fy = floorf(gy - 0.5f);
    const int fyi = (int)fy;
    const int cy0 = min(max(fyi, 0), GH - 1);
    const int cy1 = min(max(fyi + 1, 0), GH - 1);
    const float wy0 = fmaxf(1.0f - fabsf(fy + 0.5f - gy), 0.0f);
    const float wy1 = fmaxf(1.0f - fabsf(fy + 1.5f - gy), 0.0f);

    // ---- build y-collapsed row in LDS: Y = wy0*row0 + wy1*row1 ----
    // 384 f32x4 elements over 256 threads: t does f=t, and f=256+t if t<128.
    const float* gbase = grid + (size_t)n * (GH * ROW_FLOATS);
    const f32x4* row0 = (const f32x4*)(gbase + cy0 * ROW_FLOATS);
    const f32x4* row1 = (const f32x4*)(gbase + cy1 * ROW_FLOATS);
    f32x4* Y4 = (f32x4*)yrow;
    {
        const f32x4 r0 = row0[t];
        const f32x4 r1 = row1[t];
        Y4[t] = wy0 * r0 + wy1 * r1;
        if (t < 128) {
            const f32x4 r0b = row0[256 + t];
            const f32x4 r1b = row1[256 + t];
            Y4[256 + t] = wy0 * r0b + wy1 * r1b;
        }
    }
    __syncthreads();

    // ---- each thread produces 3 flat output float4s (dense stores) ----
    f32x4* __restrict__ out4 = (f32x4*)out + (size_t)b * 768;

#pragma unroll
    for (int s = 0; s < 3; ++s) {
        const int e = s * 256 + t;             // flat float4 index in block
        const int p = e / 3;                   // local pixel (magic-mul)
        const int part = e - 3 * p;            // which float4 of that pixel

        // per-pixel x interpolation
        const int x = base_x + p;
        const float gx = (x + 0.5f) * ((float)GW / (float)IMW);
        const float fx = floorf(gx - 0.5f);
        const float wx0 = fmaxf(1.0f - fabsf(fx + 0.5f - gx), 0.0f);
        const float wx1 = fmaxf(1.0f - fabsf(fx + 1.5f - gx), 0.0f);
        const int cx0 = min(max((int)fx, 0), GW - 1);
        const int cx1 = min(max((int)fx + 1, 0), GW - 1);

        // per-pixel z interpolation (guide-dependent)
        const float gz = guide[P0 + p] * (float)GD;
        const float fz = floorf(gz - 0.5f);
        const float wz0 = fmaxf(1.0f - fabsf(fz + 0.5f - gz), 0.0f);
        const float wz1 = fmaxf(1.0f - fabsf(fz + 1.5f - gz), 0.0f);
        const int cz0 = min(max((int)fz, 0), GD - 1);
        const int cz1 = min(max((int)fz + 1, 0), GD - 1);

        const int b00 = cx0 * CELL_DW + cz0 * Z_DW + part * 4;
        const int b01 = cx0 * CELL_DW + cz1 * Z_DW + part * 4;
        const int b10 = cx1 * CELL_DW + cz0 * Z_DW + part * 4;
        const int b11 = cx1 * CELL_DW + cz1 * Z_DW + part * 4;

        const f32x4 v00 = *(const f32x4*)&yrow[b00];
        const f32x4 v01 = *(const f32x4*)&yrow[b01];
        const f32x4 v10 = *(const f32x4*)&yrow[b10];
        const f32x4 v11 = *(const f32x4*)&yrow[b11];

        f32x4 acc = (wx0 * wz0) * v00;
        acc += (wx0 * wz1) * v01;
        acc += (wx1 * wz0) * v10;
        acc += (wx1 * wz1) * v11;

        out4[e] = acc;
    }
}

extern "C" void kernel_launch(void* const* d_in, const int* in_sizes, int n_in,
                              void* d_out, int out_size, void* d_ws, size_t ws_size,
                              hipStream_t stream) {
    const float* grid  = (const float*)d_in[0];
    const float* guide = (const float*)d_in[1];
    float* out = (float*)d_out;

    const int total_pixels = NBATCH * IMH * IMW;     // 4,194,304
    const int block = 256;
    const int nblocks = total_pixels / block;        // 16384, exact

    bilateral_slice_kernel<<<nblocks, block, 0, stream>>>(grid, guide, out);
}